// Round 16
// baseline (558.623 us; speedup 1.0000x reference)
//
#include <hip/hip_runtime.h>

#define FD 32
#define KNB 8
#define NITER 5
#define NCH 256   // edge chunks for the binning passes

#define LOG2E 1.44269504f

typedef __bf16 bf16x8 __attribute__((ext_vector_type(8)));
typedef float  f32x4  __attribute__((ext_vector_type(4)));

// Fast HW transcendentals (round-13 numerics: scale applied in gate math,
// weights stored UNSCALED -> absmax 0.0674; round-14 weight-fold regressed
// accuracy past threshold and stays reverted).
__device__ __forceinline__ float frcp_(float a) { return __builtin_amdgcn_rcpf(a); }
__device__ __forceinline__ float fexp2_(float a) { return __builtin_amdgcn_exp2f(a); }
__device__ __forceinline__ float sigmoidf_(float a) {
    return frcp_(1.0f + fexp2_(a * -LOG2E));
}
__device__ __forceinline__ float tanhf_(float a) {
    return 1.0f - 2.0f * frcp_(fexp2_(a * 2.0f * LOG2E) + 1.0f);
}

// ---------------- atomic-free CSR build (two-level counting sort) -----------
// bucket r = channel >> 8; NR = ceil(C/256) buckets.

__global__ __launch_bounds__(256) void bincount_kernel(
    const int* __restrict__ p2c, int* __restrict__ cnt1, int E, int NR)
{
    __shared__ int lds[256];
    int b = blockIdx.x;
    int per = (E + NCH - 1) / NCH;
    int s0 = b * per, s1 = s0 + per; if (s1 > E) s1 = E;
    int t = threadIdx.x;
    if (t < NR) lds[t] = 0;
    __syncthreads();
    for (int e = s0 + t; e < s1; e += 256)
        atomicAdd(&lds[p2c[e] >> 8], 1);
    __syncthreads();
    if (t < NR) cnt1[(size_t)b * NR + t] = lds[t];
}

__global__ __launch_bounds__(256) void scan_chunks_kernel(
    int* __restrict__ cnt1, int* __restrict__ bstart, int NR, int E)
{
    __shared__ int tt[256];
    int t = threadIdx.x;
    int tot = 0;
    if (t < NR)
        for (int b = 0; b < NCH; b++) tot += cnt1[(size_t)b * NR + t];
    tt[t] = (t < NR) ? tot : 0;
    __syncthreads();
    for (int d = 1; d < 256; d <<= 1) {
        int v = (t >= d) ? tt[t - d] : 0;
        __syncthreads();
        tt[t] += v;
        __syncthreads();
    }
    if (t < NR) {
        int run = (t == 0) ? 0 : tt[t - 1];
        bstart[t] = run;
        for (int b = 0; b < NCH; b++) {
            int v = cnt1[(size_t)b * NR + t];
            cnt1[(size_t)b * NR + t] = run;
            run += v;
        }
        if (t == NR - 1) bstart[NR] = E;
    }
}

__global__ __launch_bounds__(256) void binfill_kernel(
    const int* __restrict__ p2c, const int* __restrict__ cnt1,
    int2* __restrict__ ebuf, int E, int NR)
{
    __shared__ int cur[256];
    int b = blockIdx.x;
    int per = (E + NCH - 1) / NCH;
    int s0 = b * per, s1 = s0 + per; if (s1 > E) s1 = E;
    int t = threadIdx.x;
    if (t < NR) cur[t] = cnt1[(size_t)b * NR + t];
    __syncthreads();
    for (int e = s0 + t; e < s1; e += 256) {
        int ch = p2c[e];
        int slot = atomicAdd(&cur[ch >> 8], 1);
        ebuf[slot] = make_int2(e >> 3, ch);   // (path id, channel); KNB == 8
    }
}

__global__ __launch_bounds__(256) void buckscan_kernel(
    const int2* __restrict__ ebuf, const int* __restrict__ bstart,
    int* __restrict__ offsets, int* __restrict__ bsum, int C)
{
    __shared__ int h[256];
    __shared__ int sc[256];
    int r = blockIdx.x;
    int t = threadIdx.x;
    h[t] = 0;
    __syncthreads();
    int s0 = bstart[r], s1 = bstart[r + 1];
    for (int i = s0 + t; i < s1; i += 256)
        atomicAdd(&h[ebuf[i].y & 255], 1);
    __syncthreads();
    int mine = h[t];
    sc[t] = mine;
    __syncthreads();
    #pragma unroll
    for (int d = 1; d < 256; d <<= 1) {
        int v = (t >= d) ? sc[t - d] : 0;
        __syncthreads();
        sc[t] += v;
        __syncthreads();
    }
    int c = (r << 8) + t;
    if (c < C) offsets[c] = sc[t] - mine;   // exclusive within bucket
    if (t == 255) bsum[r] = sc[255];
}

__global__ __launch_bounds__(256) void scan_bsums_kernel(
    const int* __restrict__ bsum, int* __restrict__ bbase,
    int* __restrict__ offsets, int NR, int C, int E)
{
    __shared__ int sc[256];
    int t = threadIdx.x;
    int mine = (t < NR) ? bsum[t] : 0;
    sc[t] = mine;
    __syncthreads();
    #pragma unroll
    for (int d = 1; d < 256; d <<= 1) {
        int v = (t >= d) ? sc[t - d] : 0;
        __syncthreads();
        sc[t] += v;
        __syncthreads();
    }
    if (t < NR) bbase[t] = sc[t] - mine;
    if (t == 0) offsets[C] = E;
}

__global__ __launch_bounds__(256) void addback_kernel(
    int* __restrict__ offsets, const int* __restrict__ bbase, int C)
{
    int c = blockIdx.x * blockDim.x + threadIdx.x;
    if (c < C) offsets[c] += bbase[c >> 8];
}

__global__ __launch_bounds__(256) void buckfill_kernel(
    const int2* __restrict__ ebuf, const int* __restrict__ bstart,
    const int* __restrict__ offsets, int* __restrict__ elist, int C)
{
    __shared__ int cur[256];
    int r = blockIdx.x;
    int t = threadIdx.x;
    int c = (r << 8) + t;
    cur[t] = (c < C) ? offsets[c] : 0;
    __syncthreads();
    int s0 = bstart[r], s1 = bstart[r + 1];
    for (int i = s0 + t; i < s1; i += 256) {
        int2 v = ebuf[i];
        int slot = atomicAdd(&cur[v.y & 255], 1);
        elist[slot] = v.x;
    }
}

// ---------------- init: h_c copy + bf16 shadow in one pass ------------------

__global__ __launch_bounds__(256) void hc_init_kernel(
    const float* __restrict__ src, float* __restrict__ h_c,
    __bf16* __restrict__ dst, int n8)
{
    int i = blockIdx.x * blockDim.x + threadIdx.x;
    if (i >= n8) return;
    const float4* s = (const float4*)(src + (size_t)i * 8);
    float4 u = s[0], v = s[1];
    float4* d = (float4*)(h_c + (size_t)i * 8);
    d[0] = u; d[1] = v;
    bf16x8 o;
    o[0]=(__bf16)u.x; o[1]=(__bf16)u.y; o[2]=(__bf16)u.z; o[3]=(__bf16)u.w;
    o[4]=(__bf16)v.x; o[5]=(__bf16)v.y; o[6]=(__bf16)v.z; o[7]=(__bf16)v.w;
    ((bf16x8*)dst)[i] = o;
}

// ---------------- weight pre-conversion (UNSCALED, round-13 numerics) -------
__global__ __launch_bounds__(256) void wconv_kernel(
    const float* __restrict__ W1i, const float* __restrict__ W1h,
    const float* __restrict__ W2i, const float* __restrict__ W2h,
    __bf16* __restrict__ w1x, __bf16* __restrict__ w1h,
    __bf16* __restrict__ w2xH, __bf16* __restrict__ w2xL,
    __bf16* __restrict__ w2hH, __bf16* __restrict__ w2hL)
{
    int i = blockIdx.x * blockDim.x + threadIdx.x;
    if (i >= 96 * FD) return;
    w1x[i] = (__bf16)W1i[i];
    w1h[i] = (__bf16)W1h[i];
    float c = W2i[i]; __bf16 ch = (__bf16)c;
    w2xH[i] = ch; w2xL[i] = (__bf16)(c - (float)ch);
    float d = W2h[i]; __bf16 dh = (__bf16)d;
    w2hH[i] = dh; w2hL[i] = (__bf16)(d - (float)dh);
}

// ---------------- fused path kernel v6: 1-wave blocks + next-tile prefetch --
#define HLP 40   // bf16 row pitch: 80 B, 16B-aligned, 2-way-max bank aliasing
__global__ __launch_bounds__(64) void path_fused_kernel(
    float* __restrict__ h_p, const int* __restrict__ p2c,
    const __bf16* __restrict__ hcb,
    const __bf16* __restrict__ w1x, const __bf16* __restrict__ w1h,
    const float* __restrict__ bih, const float* __restrict__ bhh,
    __bf16* __restrict__ hpb, int ntiles16)
{
    __shared__ __bf16 hl[16][HLP];
    const int lane = threadIdx.x & 63;
    const int c    = lane & 15;
    const int kg   = lane >> 4;

    bf16x8 Bx[6], Bh[6];
    #pragma unroll
    for (int t = 0; t < 6; t++) {
        Bx[t] = *(const bf16x8*)(w1x + (size_t)(16*t + c) * FD + 8*kg);
        Bh[t] = *(const bf16x8*)(w1h + (size_t)(16*t + c) * FD + 8*kg);
    }
    f32x4 cin_rz[4], cin_xn[2], cin_hn[2];
    #pragma unroll
    for (int t = 0; t < 4; t++) {
        float b = bih[16*t + c] + bhh[16*t + c];
        cin_rz[t] = (f32x4){b, b, b, b};
    }
    #pragma unroll
    for (int fi = 0; fi < 2; fi++) {
        float bi = bih[64 + 16*fi + c];
        float bh = bhh[64 + 16*fi + c];
        cin_xn[fi] = (f32x4){bi, bi, bi, bi};
        cin_hn[fi] = (f32x4){bh, bh, bh, bh};
    }

    int tile = blockIdx.x;
    if (tile >= ntiles16) return;

    float ch_[8]; int4 cia, cib;
    {
        const int rbase = tile * 16 + 4*kg;
        #pragma unroll
        for (int q = 0; q < 4; q++)
            #pragma unroll
            for (int fi = 0; fi < 2; fi++)
                ch_[2*q + fi] = h_p[(size_t)(rbase + q) * FD + c + 16*fi];
        const int4* pp = (const int4*)(p2c + (size_t)(tile * 16 + c) * KNB);
        cia = pp[0]; cib = pp[1];
    }

    while (true) {
        const int blk0 = tile * 16;
        const int rbase = blk0 + 4*kg;
        const int nt = tile + gridDim.x;
        const bool hasN = (nt < ntiles16);

        float hD[8];
        #pragma unroll
        for (int q = 0; q < 4; q++)
            #pragma unroll
            for (int fi = 0; fi < 2; fi++) {
                float v = ch_[2*q + fi];
                hD[2*q + fi] = v;
                hl[4*kg + q][c + 16*fi] = (__bf16)v;
            }
        int idxA[KNB] = {cia.x, cia.y, cia.z, cia.w, cib.x, cib.y, cib.z, cib.w};
        bf16x8 Ax[KNB];
        #pragma unroll
        for (int k = 0; k < KNB; k++)
            Ax[k] = *(const bf16x8*)(hcb + (size_t)idxA[k] * FD + 8*kg);

        float nh[8]; int4 nia, nib;
        if (hasN) {
            const int nrbase = nt * 16 + 4*kg;
            #pragma unroll
            for (int q = 0; q < 4; q++)
                #pragma unroll
                for (int fi = 0; fi < 2; fi++)
                    nh[2*q + fi] = h_p[(size_t)(nrbase + q) * FD + c + 16*fi];
            const int4* pp = (const int4*)(p2c + (size_t)(nt * 16 + c) * KNB);
            nia = pp[0]; nib = pp[1];
        }

        #pragma unroll
        for (int k = 0; k < KNB; k++) {
            bf16x8 Ah = *(const bf16x8*)&hl[c][8*kg];

            f32x4 arz[4], xn[2], hn[2];
            #pragma unroll
            for (int t = 0; t < 4; t++) {
                arz[t] = __builtin_amdgcn_mfma_f32_16x16x32_bf16(Ax[k], Bx[t], cin_rz[t], 0, 0, 0);
                arz[t] = __builtin_amdgcn_mfma_f32_16x16x32_bf16(Ah,    Bh[t], arz[t],   0, 0, 0);
            }
            #pragma unroll
            for (int fi = 0; fi < 2; fi++) {
                xn[fi] = __builtin_amdgcn_mfma_f32_16x16x32_bf16(Ax[k], Bx[4+fi], cin_xn[fi], 0, 0, 0);
                hn[fi] = __builtin_amdgcn_mfma_f32_16x16x32_bf16(Ah,    Bh[4+fi], cin_hn[fi], 0, 0, 0);
            }

            #pragma unroll
            for (int q = 0; q < 4; q++)
                #pragma unroll
                for (int fi = 0; fi < 2; fi++) {
                    float r = sigmoidf_(arz[fi][q]);
                    float z = sigmoidf_(arz[2+fi][q]);
                    float n = tanhf_(fmaf(r, hn[fi][q], xn[fi][q]));
                    float ho = hD[2*q + fi];
                    float hv = fmaf(z, ho - n, n);
                    hD[2*q + fi] = hv;
                    hl[4*kg + q][c + 16*fi] = (__bf16)hv;
                }
        }

        #pragma unroll
        for (int q = 0; q < 4; q++)
            #pragma unroll
            for (int fi = 0; fi < 2; fi++)
                h_p[(size_t)(rbase + q) * FD + c + 16*fi] = hD[2*q + fi];

        {
            int r  = lane >> 2;
            int c0 = (lane & 3) * 8;
            bf16x8 o = *(const bf16x8*)&hl[r][c0];
            *(bf16x8*)(hpb + ((size_t)(blk0 + r)) * FD + c0) = o;
        }

        if (!hasN) break;
        #pragma unroll
        for (int j = 0; j < 8; j++) ch_[j] = nh[j];
        cia = nia; cib = nib;
        tile = nt;
    }
}

// ---------------- fused gather + channel GRU2 (MFMA, preconv weights) -------
// 2-wave blocks; gather 8-deep (avg 32 edges/channel -> 4 dependency rounds).
__global__ __launch_bounds__(128) void gchannel_kernel(
    const __bf16* __restrict__ hpb, const int* __restrict__ offsets,
    const int* __restrict__ elist, float* __restrict__ h_c,
    const __bf16* __restrict__ w2xH, const __bf16* __restrict__ w2xL,
    const __bf16* __restrict__ w2hH, const __bf16* __restrict__ w2hL,
    const float* __restrict__ bih, const float* __restrict__ bhh,
    __bf16* __restrict__ hcb, int C)
{
    const int tid  = threadIdx.x;
    const int wid  = tid >> 6;          // 0..1
    const int lane = tid & 63;
    const int c    = lane & 15;
    const int kg   = lane >> 4;
    const int blk0 = blockIdx.x * 32;
    const int chA  = blk0 + wid*16 + c;

    // gather: 8-deep, dual accumulator banks (8 loads in flight per round)
    float xr[8], xs[8];
    #pragma unroll
    for (int j = 0; j < 8; j++) { xr[j] = 0.f; xs[j] = 0.f; }
    int s = 0, e = 0;
    if (chA < C) { s = offsets[chA]; e = offsets[chA + 1]; }
    int i = s;
    for (; i + 8 <= e; i += 8) {
        int e0 = elist[i],     e1 = elist[i + 1], e2 = elist[i + 2], e3 = elist[i + 3];
        int e4 = elist[i + 4], e5 = elist[i + 5], e6 = elist[i + 6], e7 = elist[i + 7];
        bf16x8 v0 = *(const bf16x8*)(hpb + (size_t)e0 * FD + 8*kg);
        bf16x8 v1 = *(const bf16x8*)(hpb + (size_t)e1 * FD + 8*kg);
        bf16x8 v2 = *(const bf16x8*)(hpb + (size_t)e2 * FD + 8*kg);
        bf16x8 v3 = *(const bf16x8*)(hpb + (size_t)e3 * FD + 8*kg);
        bf16x8 v4 = *(const bf16x8*)(hpb + (size_t)e4 * FD + 8*kg);
        bf16x8 v5 = *(const bf16x8*)(hpb + (size_t)e5 * FD + 8*kg);
        bf16x8 v6 = *(const bf16x8*)(hpb + (size_t)e6 * FD + 8*kg);
        bf16x8 v7 = *(const bf16x8*)(hpb + (size_t)e7 * FD + 8*kg);
        #pragma unroll
        for (int j = 0; j < 8; j++) {
            xr[j] += ((float)v0[j] + (float)v2[j]) + ((float)v4[j] + (float)v6[j]);
            xs[j] += ((float)v1[j] + (float)v3[j]) + ((float)v5[j] + (float)v7[j]);
        }
    }
    for (; i + 2 <= e; i += 2) {
        int e0 = elist[i], e1 = elist[i + 1];
        bf16x8 v0 = *(const bf16x8*)(hpb + (size_t)e0 * FD + 8*kg);
        bf16x8 v1 = *(const bf16x8*)(hpb + (size_t)e1 * FD + 8*kg);
        #pragma unroll
        for (int j = 0; j < 8; j++) {
            xr[j] += (float)v0[j];
            xs[j] += (float)v1[j];
        }
    }
    if (i < e) {
        bf16x8 v0 = *(const bf16x8*)(hpb + (size_t)elist[i] * FD + 8*kg);
        #pragma unroll
        for (int j = 0; j < 8; j++) xr[j] += (float)v0[j];
    }
    #pragma unroll
    for (int j = 0; j < 8; j++) xr[j] += xs[j];

    float hr[8];
    if (chA < C) {
        const float4* ha = (const float4*)(h_c + (size_t)chA * FD + 8*kg);
        float4 h0 = ha[0], h1 = ha[1];
        hr[0]=h0.x; hr[1]=h0.y; hr[2]=h0.z; hr[3]=h0.w;
        hr[4]=h1.x; hr[5]=h1.y; hr[6]=h1.z; hr[7]=h1.w;
    } else {
        #pragma unroll
        for (int j = 0; j < 8; j++) hr[j] = 0.f;
    }
    bf16x8 AxH, AxL, AhH, AhL;
    #pragma unroll
    for (int j = 0; j < 8; j++) {
        __bf16 xh = (__bf16)xr[j]; AxH[j] = xh; AxL[j] = (__bf16)(xr[j] - (float)xh);
        __bf16 hh = (__bf16)hr[j]; AhH[j] = hh; AhL[j] = (__bf16)(hr[j] - (float)hh);
    }

    f32x4 cin_rz[4], cin_xn[2], cin_hn[2];
    #pragma unroll
    for (int t = 0; t < 4; t++) {
        float b = bih[16*t + c] + bhh[16*t + c];
        cin_rz[t] = (f32x4){b, b, b, b};
    }
    #pragma unroll
    for (int fi = 0; fi < 2; fi++) {
        float bi = bih[64 + 16*fi + c];
        float bh = bhh[64 + 16*fi + c];
        cin_xn[fi] = (f32x4){bi, bi, bi, bi};
        cin_hn[fi] = (f32x4){bh, bh, bh, bh};
    }

    f32x4 arz[4], xn[2], hn[2];
    #pragma unroll
    for (int t = 0; t < 4; t++) {
        size_t wo = (size_t)(16*t + c) * FD + 8*kg;
        bf16x8 BxH_ = *(const bf16x8*)(w2xH + wo);
        bf16x8 BxL_ = *(const bf16x8*)(w2xL + wo);
        bf16x8 BhH_ = *(const bf16x8*)(w2hH + wo);
        bf16x8 BhL_ = *(const bf16x8*)(w2hL + wo);
        f32x4 a = cin_rz[t];
        a = __builtin_amdgcn_mfma_f32_16x16x32_bf16(AxH, BxH_, a, 0, 0, 0);
        a = __builtin_amdgcn_mfma_f32_16x16x32_bf16(AxH, BxL_, a, 0, 0, 0);
        a = __builtin_amdgcn_mfma_f32_16x16x32_bf16(AxL, BxH_, a, 0, 0, 0);
        a = __builtin_amdgcn_mfma_f32_16x16x32_bf16(AhH, BhH_, a, 0, 0, 0);
        a = __builtin_amdgcn_mfma_f32_16x16x32_bf16(AhH, BhL_, a, 0, 0, 0);
        a = __builtin_amdgcn_mfma_f32_16x16x32_bf16(AhL, BhH_, a, 0, 0, 0);
        arz[t] = a;
    }
    #pragma unroll
    for (int fi = 0; fi < 2; fi++) {
        size_t wo = (size_t)(16*(4+fi) + c) * FD + 8*kg;
        bf16x8 BxH_ = *(const bf16x8*)(w2xH + wo);
        bf16x8 BxL_ = *(const bf16x8*)(w2xL + wo);
        bf16x8 BhH_ = *(const bf16x8*)(w2hH + wo);
        bf16x8 BhL_ = *(const bf16x8*)(w2hL + wo);
        f32x4 a = cin_xn[fi];
        a = __builtin_amdgcn_mfma_f32_16x16x32_bf16(AxH, BxH_, a, 0, 0, 0);
        a = __builtin_amdgcn_mfma_f32_16x16x32_bf16(AxH, BxL_, a, 0, 0, 0);
        a = __builtin_amdgcn_mfma_f32_16x16x32_bf16(AxL, BxH_, a, 0, 0, 0);
        xn[fi] = a;
        f32x4 b = cin_hn[fi];
        b = __builtin_amdgcn_mfma_f32_16x16x32_bf16(AhH, BhH_, b, 0, 0, 0);
        b = __builtin_amdgcn_mfma_f32_16x16x32_bf16(AhH, BhL_, b, 0, 0, 0);
        b = __builtin_amdgcn_mfma_f32_16x16x32_bf16(AhL, BhH_, b, 0, 0, 0);
        hn[fi] = b;
    }

    #pragma unroll
    for (int q = 0; q < 4; q++) {
        int row = blk0 + wid*16 + 4*kg + q;
        if (row < C) {
            #pragma unroll
            for (int fi = 0; fi < 2; fi++) {
                float r = sigmoidf_(arz[fi][q]);
                float z = sigmoidf_(arz[2+fi][q]);
                float n = tanhf_(fmaf(r, hn[fi][q], xn[fi][q]));
                float ho = h_c[(size_t)row * FD + c + 16*fi];
                float hv = fmaf(z, ho - n, n);
                h_c[(size_t)row * FD + c + 16*fi] = hv;
                hcb[(size_t)row * FD + c + 16*fi] = (__bf16)hv;
            }
        }
    }
}

// ---------------- fallback kernels (atomic path, raw weights) ---------------

__global__ __launch_bounds__(256) void path_update_kernel(
    const float* __restrict__ h_c, float* __restrict__ h_p,
    const int* __restrict__ p2c,
    const float* __restrict__ Wih, const float* __restrict__ Whh,
    const float* __restrict__ bih, const float* __restrict__ bhh, int P)
{
    int p = blockIdx.x * blockDim.x + threadIdx.x;
    if (p >= P) return;

    float h[FD];
    const float4* hp4 = (const float4*)(h_p + (size_t)p * FD);
    #pragma unroll
    for (int i = 0; i < FD / 4; i++) {
        float4 v = hp4[i];
        h[4*i] = v.x; h[4*i+1] = v.y; h[4*i+2] = v.z; h[4*i+3] = v.w;
    }

    int idx[KNB];
    const int4* pi = (const int4*)(p2c + (size_t)p * KNB);
    int4 i0 = pi[0], i1 = pi[1];
    idx[0]=i0.x; idx[1]=i0.y; idx[2]=i0.z; idx[3]=i0.w;
    idx[4]=i1.x; idx[5]=i1.y; idx[6]=i1.z; idx[7]=i1.w;

    for (int k = 0; k < KNB; k++) {
        float x[FD];
        const float4* xr = (const float4*)(h_c + (size_t)idx[k] * FD);
        #pragma unroll
        for (int i = 0; i < FD / 4; i++) {
            float4 v = xr[i];
            x[4*i] = v.x; x[4*i+1] = v.y; x[4*i+2] = v.z; x[4*i+3] = v.w;
        }

        float hn[FD];
        #pragma unroll 4
        for (int j = 0; j < FD; j++) {
            float air = bih[j],        ahr = bhh[j];
            float aiz = bih[FD + j],   ahz = bhh[FD + j];
            float ain = bih[2*FD + j], ahn = bhh[2*FD + j];
            #pragma unroll
            for (int i = 0; i < FD; i++) {
                air = fmaf(Wih[j*FD + i],          x[i], air);
                ahr = fmaf(Whh[j*FD + i],          h[i], ahr);
                aiz = fmaf(Wih[(FD + j)*FD + i],   x[i], aiz);
                ahz = fmaf(Whh[(FD + j)*FD + i],   h[i], ahz);
                ain = fmaf(Wih[(2*FD + j)*FD + i], x[i], ain);
                ahn = fmaf(Whh[(2*FD + j)*FD + i], h[i], ahn);
            }
            float r = sigmoidf_(air + ahr);
            float z = sigmoidf_(aiz + ahz);
            float n = tanhf_(ain + r * ahn);
            hn[j] = (1.0f - z) * n + z * h[j];
        }
        #pragma unroll
        for (int j = 0; j < FD; j++) h[j] = hn[j];
    }

    float4* hpw = (float4*)(h_p + (size_t)p * FD);
    #pragma unroll
    for (int i = 0; i < FD / 4; i++) {
        float4 v;
        v.x = h[4*i]; v.y = h[4*i+1]; v.z = h[4*i+2]; v.w = h[4*i+3];
        hpw[i] = v;
    }
}

__global__ __launch_bounds__(256) void scatter_agg_atomic_kernel(
    const float* __restrict__ h_p, const int* __restrict__ p2c,
    float* __restrict__ agg, int P)
{
    int p = blockIdx.x * blockDim.x + threadIdx.x;
    if (p >= P) return;
    const float* hr = h_p + (size_t)p * FD;
    #pragma unroll
    for (int k = 0; k < KNB; k++) {
        int c = p2c[(size_t)p * KNB + k];
        float* ar = agg + (size_t)c * FD;
        #pragma unroll
        for (int i = 0; i < FD; i++) atomicAdd(ar + i, hr[i]);
    }
}

__global__ __launch_bounds__(256) void channel_update_kernel(
    const float* __restrict__ agg, float* __restrict__ h_c,
    const float* __restrict__ Wih, const float* __restrict__ Whh,
    const float* __restrict__ bih, const float* __restrict__ bhh, int C)
{
    int c = blockIdx.x * blockDim.x + threadIdx.x;
    if (c >= C) return;

    float h[FD], x[FD];
    const float4* hr = (const float4*)(h_c + (size_t)c * FD);
    const float4* xr = (const float4*)(agg + (size_t)c * FD);
    #pragma unroll
    for (int i = 0; i < FD / 4; i++) {
        float4 v = hr[i];
        h[4*i] = v.x; h[4*i+1] = v.y; h[4*i+2] = v.z; h[4*i+3] = v.w;
        float4 w = xr[i];
        x[4*i] = w.x; x[4*i+1] = w.y; x[4*i+2] = w.z; x[4*i+3] = w.w;
    }

    float hn[FD];
    #pragma unroll 4
    for (int j = 0; j < FD; j++) {
        float air = bih[j],        ahr = bhh[j];
        float aiz = bih[FD + j],   ahz = bhh[FD + j];
        float ain = bih[2*FD + j], ahn = bhh[2*FD + j];
        #pragma unroll
        for (int i = 0; i < FD; i++) {
            air = fmaf(Wih[j*FD + i],          x[i], air);
            ahr = fmaf(Whh[j*FD + i],          h[i], ahr);
            aiz = fmaf(Wih[(FD + j)*FD + i],   x[i], aiz);
            ahz = fmaf(Whh[(FD + j)*FD + i],   h[i], ahz);
            ain = fmaf(Wih[(2*FD + j)*FD + i], x[i], ain);
            ahn = fmaf(Whh[(2*FD + j)*FD + i], h[i], ahn);
        }
        float r = sigmoidf_(air + ahr);
        float z = sigmoidf_(aiz + ahz);
        float n = tanhf_(ain + r * ahn);
        hn[j] = (1.0f - z) * n + z * h[j];
    }

    float4* hw = (float4*)(h_c + (size_t)c * FD);
    #pragma unroll
    for (int i = 0; i < FD / 4; i++) {
        float4 v;
        v.x = hn[4*i]; v.y = hn[4*i+1]; v.z = hn[4*i+2]; v.w = hn[4*i+3];
        hw[i] = v;
    }
}

extern "C" void kernel_launch(void* const* d_in, const int* in_sizes, int n_in,
                              void* d_out, int out_size, void* d_ws, size_t ws_size,
                              hipStream_t stream) {
    const float* paths    = (const float*)d_in[0];
    const float* channels = (const float*)d_in[1];
    const int*   p2c      = (const int*)d_in[2];
    const float* Wih1 = (const float*)d_in[3];
    const float* Whh1 = (const float*)d_in[4];
    const float* bih1 = (const float*)d_in[5];
    const float* bhh1 = (const float*)d_in[6];
    const float* Wih2 = (const float*)d_in[7];
    const float* Whh2 = (const float*)d_in[8];
    const float* bih2 = (const float*)d_in[9];
    const float* bhh2 = (const float*)d_in[10];

    const int P = in_sizes[0] / FD;     // 200000
    const int C = in_sizes[1] / FD;     // 50000
    const int E = P * KNB;              // 1.6M edges
    const int NR = (C + 255) >> 8;      // 196 buckets

    float* h_p = (float*)d_out;                  // [P*FD]
    float* h_c = h_p + (size_t)P * FD;           // [C*FD]

    // ws: bsum[NR] bbase[NR] | offsets[C+1] | bstart[NR+1] | elist[E] | hcb |
    //     wbufs(6) | UNION{ build: ebuf[E](int2)+cnt1[NCH*NR] | iter: hpb }
    char* ws = (char*)d_ws;
    size_t bs_off  = 0;
    size_t ofs_off = (bs_off + (size_t)(2 * NR) * 4 + 255) & ~(size_t)255;
    size_t bst_off = (ofs_off + (size_t)(C + 1) * 4 + 255) & ~(size_t)255;
    size_t el_off  = (bst_off + (size_t)(NR + 1) * 4 + 255) & ~(size_t)255;
    size_t hcb_off = (el_off + (size_t)E * 4 + 255) & ~(size_t)255;
    size_t wb_off  = (hcb_off + (size_t)C * FD * 2 + 255) & ~(size_t)255;
    size_t wmat_b  = (size_t)96 * FD * 2;                 // 6 KB per matrix
    size_t uni_off = (wb_off + 6 * wmat_b + 255) & ~(size_t)255;
    size_t ebuf_b  = (size_t)E * 8;
    size_t cnt1_b  = (size_t)NCH * NR * 4;
    size_t hpb_b   = (size_t)P * FD * 2;
    size_t bld_b   = ebuf_b + cnt1_b;
    size_t uni_b   = (hpb_b > bld_b) ? hpb_b : bld_b;

    int*    bsum    = (int*)(ws + bs_off);
    int*    bbase   = bsum + NR;
    int*    offsets = (int*)(ws + ofs_off);
    int*    bstart  = (int*)(ws + bst_off);
    int*    elist   = (int*)(ws + el_off);
    __bf16* hcb     = (__bf16*)(ws + hcb_off);
    __bf16* w1x     = (__bf16*)(ws + wb_off);
    __bf16* w1h     = (__bf16*)(ws + wb_off + 1 * wmat_b);
    __bf16* w2xH    = (__bf16*)(ws + wb_off + 2 * wmat_b);
    __bf16* w2xL    = (__bf16*)(ws + wb_off + 3 * wmat_b);
    __bf16* w2hH    = (__bf16*)(ws + wb_off + 4 * wmat_b);
    __bf16* w2hL    = (__bf16*)(ws + wb_off + 5 * wmat_b);
    int2*   ebuf    = (int2*)(ws + uni_off);
    int*    cnt1    = (int*)(ws + uni_off + ebuf_b);
    __bf16* hpb     = (__bf16*)(ws + uni_off);   // time-disjoint w/ ebuf/cnt1

    const bool mfma_ok = (P % 64 == 0) && (C <= 65536);
    const bool tier1 = mfma_ok && (ws_size >= uni_off + uni_b);

    dim3 pb(256), pg((P + 255) / 256);
    dim3 cb(256), cg((C + 255) / 256);

    if (tier1) {
        hipMemcpyAsync(h_p, paths, (size_t)P * FD * sizeof(float),
                       hipMemcpyDeviceToDevice, stream);
        int n8 = C * FD / 8;
        hc_init_kernel<<<(n8 + 255) / 256, 256, 0, stream>>>(channels, h_c, hcb, n8);
        wconv_kernel<<<(96 * FD + 255) / 256, 256, 0, stream>>>(
            Wih1, Whh1, Wih2, Whh2, w1x, w1h, w2xH, w2xL, w2hH, w2hL);

        bincount_kernel<<<NCH, 256, 0, stream>>>(p2c, cnt1, E, NR);
        scan_chunks_kernel<<<1, 256, 0, stream>>>(cnt1, bstart, NR, E);
        binfill_kernel<<<NCH, 256, 0, stream>>>(p2c, cnt1, ebuf, E, NR);
        buckscan_kernel<<<NR, 256, 0, stream>>>(ebuf, bstart, offsets, bsum, C);
        scan_bsums_kernel<<<1, 256, 0, stream>>>(bsum, bbase, offsets, NR, C, E);
        addback_kernel<<<cg, cb, 0, stream>>>(offsets, bbase, C);
        buckfill_kernel<<<NR, 256, 0, stream>>>(ebuf, bstart, offsets, elist, C);

        const int ntiles16 = P / 16;                    // 12500 wave-tiles
        int pgrid = ntiles16 < 5120 ? ntiles16 : 5120;  // 5 waves/SIMD @ VGPR 96
        dim3 xg((C + 31) / 32), xb(128);
        for (int it = 0; it < NITER; it++) {
            path_fused_kernel<<<pgrid, 64, 0, stream>>>(h_p, p2c, hcb,
                                                        w1x, w1h, bih1, bhh1,
                                                        hpb, ntiles16);
            gchannel_kernel<<<xg, xb, 0, stream>>>(hpb, offsets, elist, h_c,
                                                   w2xH, w2xL, w2hH, w2hL,
                                                   bih2, bhh2, hcb, C);
        }
    } else {
        float* agg0 = (float*)d_ws;
        size_t aggf_b = (size_t)C * FD * sizeof(float);
        hipMemcpyAsync(h_p, paths, (size_t)P * FD * sizeof(float),
                       hipMemcpyDeviceToDevice, stream);
        hipMemcpyAsync(h_c, channels, (size_t)C * FD * sizeof(float),
                       hipMemcpyDeviceToDevice, stream);
        for (int it = 0; it < NITER; it++) {
            path_update_kernel<<<pg, pb, 0, stream>>>(h_c, h_p, p2c,
                                                      Wih1, Whh1, bih1, bhh1, P);
            hipMemsetAsync(agg0, 0, aggf_b, stream);
            scatter_agg_atomic_kernel<<<pg, pb, 0, stream>>>(h_p, p2c, agg0, P);
            channel_update_kernel<<<cg, cb, 0, stream>>>(agg0, h_c,
                                                         Wih2, Whh2, bih2, bhh2, C);
        }
    }
}

// Round 17
// 534.067 us; speedup vs baseline: 1.0460x; 1.0460x over previous
//
#include <hip/hip_runtime.h>

#define FD 32
#define KNB 8
#define NITER 5
#define NCH 256   // edge chunks for the binning passes

#define LOG2E 1.44269504f

typedef __bf16 bf16x8 __attribute__((ext_vector_type(8)));
typedef float  f32x4  __attribute__((ext_vector_type(4)));

// Fast HW transcendentals (round-13 numerics: scale applied in gate math,
// weights stored UNSCALED -> absmax 0.0674; round-14 weight-fold regressed
// accuracy past threshold and stays reverted).
__device__ __forceinline__ float frcp_(float a) { return __builtin_amdgcn_rcpf(a); }
__device__ __forceinline__ float fexp2_(float a) { return __builtin_amdgcn_exp2f(a); }
__device__ __forceinline__ float sigmoidf_(float a) {
    return frcp_(1.0f + fexp2_(a * -LOG2E));
}
__device__ __forceinline__ float tanhf_(float a) {
    return 1.0f - 2.0f * frcp_(fexp2_(a * 2.0f * LOG2E) + 1.0f);
}

// ---------------- atomic-free CSR build (two-level counting sort) -----------
// bucket r = channel >> 8; NR = ceil(C/256) buckets.

__global__ __launch_bounds__(256) void bincount_kernel(
    const int* __restrict__ p2c, int* __restrict__ cnt1, int E, int NR)
{
    __shared__ int lds[256];
    int b = blockIdx.x;
    int per = (E + NCH - 1) / NCH;
    int s0 = b * per, s1 = s0 + per; if (s1 > E) s1 = E;
    int t = threadIdx.x;
    if (t < NR) lds[t] = 0;
    __syncthreads();
    for (int e = s0 + t; e < s1; e += 256)
        atomicAdd(&lds[p2c[e] >> 8], 1);
    __syncthreads();
    if (t < NR) cnt1[(size_t)b * NR + t] = lds[t];
}

__global__ __launch_bounds__(256) void scan_chunks_kernel(
    int* __restrict__ cnt1, int* __restrict__ bstart, int NR, int E)
{
    __shared__ int tt[256];
    int t = threadIdx.x;
    int tot = 0;
    if (t < NR)
        for (int b = 0; b < NCH; b++) tot += cnt1[(size_t)b * NR + t];
    tt[t] = (t < NR) ? tot : 0;
    __syncthreads();
    for (int d = 1; d < 256; d <<= 1) {
        int v = (t >= d) ? tt[t - d] : 0;
        __syncthreads();
        tt[t] += v;
        __syncthreads();
    }
    if (t < NR) {
        int run = (t == 0) ? 0 : tt[t - 1];
        bstart[t] = run;
        for (int b = 0; b < NCH; b++) {
            int v = cnt1[(size_t)b * NR + t];
            cnt1[(size_t)b * NR + t] = run;
            run += v;
        }
        if (t == NR - 1) bstart[NR] = E;
    }
}

__global__ __launch_bounds__(256) void binfill_kernel(
    const int* __restrict__ p2c, const int* __restrict__ cnt1,
    int2* __restrict__ ebuf, int E, int NR)
{
    __shared__ int cur[256];
    int b = blockIdx.x;
    int per = (E + NCH - 1) / NCH;
    int s0 = b * per, s1 = s0 + per; if (s1 > E) s1 = E;
    int t = threadIdx.x;
    if (t < NR) cur[t] = cnt1[(size_t)b * NR + t];
    __syncthreads();
    for (int e = s0 + t; e < s1; e += 256) {
        int ch = p2c[e];
        int slot = atomicAdd(&cur[ch >> 8], 1);
        ebuf[slot] = make_int2(e >> 3, ch);   // (path id, channel); KNB == 8
    }
}

__global__ __launch_bounds__(256) void buckscan_kernel(
    const int2* __restrict__ ebuf, const int* __restrict__ bstart,
    int* __restrict__ offsets, int* __restrict__ bsum, int C)
{
    __shared__ int h[256];
    __shared__ int sc[256];
    int r = blockIdx.x;
    int t = threadIdx.x;
    h[t] = 0;
    __syncthreads();
    int s0 = bstart[r], s1 = bstart[r + 1];
    for (int i = s0 + t; i < s1; i += 256)
        atomicAdd(&h[ebuf[i].y & 255], 1);
    __syncthreads();
    int mine = h[t];
    sc[t] = mine;
    __syncthreads();
    #pragma unroll
    for (int d = 1; d < 256; d <<= 1) {
        int v = (t >= d) ? sc[t - d] : 0;
        __syncthreads();
        sc[t] += v;
        __syncthreads();
    }
    int c = (r << 8) + t;
    if (c < C) offsets[c] = sc[t] - mine;   // exclusive within bucket
    if (t == 255) bsum[r] = sc[255];
}

__global__ __launch_bounds__(256) void scan_bsums_kernel(
    const int* __restrict__ bsum, int* __restrict__ bbase,
    int* __restrict__ offsets, int NR, int C, int E)
{
    __shared__ int sc[256];
    int t = threadIdx.x;
    int mine = (t < NR) ? bsum[t] : 0;
    sc[t] = mine;
    __syncthreads();
    #pragma unroll
    for (int d = 1; d < 256; d <<= 1) {
        int v = (t >= d) ? sc[t - d] : 0;
        __syncthreads();
        sc[t] += v;
        __syncthreads();
    }
    if (t < NR) bbase[t] = sc[t] - mine;
    if (t == 0) offsets[C] = E;
}

__global__ __launch_bounds__(256) void addback_kernel(
    int* __restrict__ offsets, const int* __restrict__ bbase, int C)
{
    int c = blockIdx.x * blockDim.x + threadIdx.x;
    if (c < C) offsets[c] += bbase[c >> 8];
}

__global__ __launch_bounds__(256) void buckfill_kernel(
    const int2* __restrict__ ebuf, const int* __restrict__ bstart,
    const int* __restrict__ offsets, int* __restrict__ elist, int C)
{
    __shared__ int cur[256];
    int r = blockIdx.x;
    int t = threadIdx.x;
    int c = (r << 8) + t;
    cur[t] = (c < C) ? offsets[c] : 0;
    __syncthreads();
    int s0 = bstart[r], s1 = bstart[r + 1];
    for (int i = s0 + t; i < s1; i += 256) {
        int2 v = ebuf[i];
        int slot = atomicAdd(&cur[v.y & 255], 1);
        elist[slot] = v.x;
    }
}

// ---------------- init: h_c copy + bf16 shadow in one pass ------------------

__global__ __launch_bounds__(256) void hc_init_kernel(
    const float* __restrict__ src, float* __restrict__ h_c,
    __bf16* __restrict__ dst, int n8)
{
    int i = blockIdx.x * blockDim.x + threadIdx.x;
    if (i >= n8) return;
    const float4* s = (const float4*)(src + (size_t)i * 8);
    float4 u = s[0], v = s[1];
    float4* d = (float4*)(h_c + (size_t)i * 8);
    d[0] = u; d[1] = v;
    bf16x8 o;
    o[0]=(__bf16)u.x; o[1]=(__bf16)u.y; o[2]=(__bf16)u.z; o[3]=(__bf16)u.w;
    o[4]=(__bf16)v.x; o[5]=(__bf16)v.y; o[6]=(__bf16)v.z; o[7]=(__bf16)v.w;
    ((bf16x8*)dst)[i] = o;
}

// ---------------- weight pre-conversion (UNSCALED, round-13 numerics) -------
__global__ __launch_bounds__(256) void wconv_kernel(
    const float* __restrict__ W1i, const float* __restrict__ W1h,
    const float* __restrict__ W2i, const float* __restrict__ W2h,
    __bf16* __restrict__ w1x, __bf16* __restrict__ w1h,
    __bf16* __restrict__ w2xH, __bf16* __restrict__ w2xL,
    __bf16* __restrict__ w2hH, __bf16* __restrict__ w2hL)
{
    int i = blockIdx.x * blockDim.x + threadIdx.x;
    if (i >= 96 * FD) return;
    w1x[i] = (__bf16)W1i[i];
    w1h[i] = (__bf16)W1h[i];
    float c = W2i[i]; __bf16 ch = (__bf16)c;
    w2xH[i] = ch; w2xL[i] = (__bf16)(c - (float)ch);
    float d = W2h[i]; __bf16 dh = (__bf16)d;
    w2hH[i] = dh; w2hL[i] = (__bf16)(d - (float)dh);
}

// ---------------- fused path kernel v6: 1-wave blocks + next-tile prefetch --
#define HLP 40   // bf16 row pitch: 80 B, 16B-aligned, 2-way-max bank aliasing
__global__ __launch_bounds__(64) void path_fused_kernel(
    float* __restrict__ h_p, const int* __restrict__ p2c,
    const __bf16* __restrict__ hcb,
    const __bf16* __restrict__ w1x, const __bf16* __restrict__ w1h,
    const float* __restrict__ bih, const float* __restrict__ bhh,
    __bf16* __restrict__ hpb, int ntiles16)
{
    __shared__ __bf16 hl[16][HLP];
    const int lane = threadIdx.x & 63;
    const int c    = lane & 15;
    const int kg   = lane >> 4;

    bf16x8 Bx[6], Bh[6];
    #pragma unroll
    for (int t = 0; t < 6; t++) {
        Bx[t] = *(const bf16x8*)(w1x + (size_t)(16*t + c) * FD + 8*kg);
        Bh[t] = *(const bf16x8*)(w1h + (size_t)(16*t + c) * FD + 8*kg);
    }
    f32x4 cin_rz[4], cin_xn[2], cin_hn[2];
    #pragma unroll
    for (int t = 0; t < 4; t++) {
        float b = bih[16*t + c] + bhh[16*t + c];
        cin_rz[t] = (f32x4){b, b, b, b};
    }
    #pragma unroll
    for (int fi = 0; fi < 2; fi++) {
        float bi = bih[64 + 16*fi + c];
        float bh = bhh[64 + 16*fi + c];
        cin_xn[fi] = (f32x4){bi, bi, bi, bi};
        cin_hn[fi] = (f32x4){bh, bh, bh, bh};
    }

    int tile = blockIdx.x;
    if (tile >= ntiles16) return;

    float ch_[8]; int4 cia, cib;
    {
        const int rbase = tile * 16 + 4*kg;
        #pragma unroll
        for (int q = 0; q < 4; q++)
            #pragma unroll
            for (int fi = 0; fi < 2; fi++)
                ch_[2*q + fi] = h_p[(size_t)(rbase + q) * FD + c + 16*fi];
        const int4* pp = (const int4*)(p2c + (size_t)(tile * 16 + c) * KNB);
        cia = pp[0]; cib = pp[1];
    }

    while (true) {
        const int blk0 = tile * 16;
        const int rbase = blk0 + 4*kg;
        const int nt = tile + gridDim.x;
        const bool hasN = (nt < ntiles16);

        float hD[8];
        #pragma unroll
        for (int q = 0; q < 4; q++)
            #pragma unroll
            for (int fi = 0; fi < 2; fi++) {
                float v = ch_[2*q + fi];
                hD[2*q + fi] = v;
                hl[4*kg + q][c + 16*fi] = (__bf16)v;
            }
        int idxA[KNB] = {cia.x, cia.y, cia.z, cia.w, cib.x, cib.y, cib.z, cib.w};
        bf16x8 Ax[KNB];
        #pragma unroll
        for (int k = 0; k < KNB; k++)
            Ax[k] = *(const bf16x8*)(hcb + (size_t)idxA[k] * FD + 8*kg);

        float nh[8]; int4 nia, nib;
        if (hasN) {
            const int nrbase = nt * 16 + 4*kg;
            #pragma unroll
            for (int q = 0; q < 4; q++)
                #pragma unroll
                for (int fi = 0; fi < 2; fi++)
                    nh[2*q + fi] = h_p[(size_t)(nrbase + q) * FD + c + 16*fi];
            const int4* pp = (const int4*)(p2c + (size_t)(nt * 16 + c) * KNB);
            nia = pp[0]; nib = pp[1];
        }

        #pragma unroll
        for (int k = 0; k < KNB; k++) {
            bf16x8 Ah = *(const bf16x8*)&hl[c][8*kg];

            f32x4 arz[4], xn[2], hn[2];
            #pragma unroll
            for (int t = 0; t < 4; t++) {
                arz[t] = __builtin_amdgcn_mfma_f32_16x16x32_bf16(Ax[k], Bx[t], cin_rz[t], 0, 0, 0);
                arz[t] = __builtin_amdgcn_mfma_f32_16x16x32_bf16(Ah,    Bh[t], arz[t],   0, 0, 0);
            }
            #pragma unroll
            for (int fi = 0; fi < 2; fi++) {
                xn[fi] = __builtin_amdgcn_mfma_f32_16x16x32_bf16(Ax[k], Bx[4+fi], cin_xn[fi], 0, 0, 0);
                hn[fi] = __builtin_amdgcn_mfma_f32_16x16x32_bf16(Ah,    Bh[4+fi], cin_hn[fi], 0, 0, 0);
            }

            #pragma unroll
            for (int q = 0; q < 4; q++)
                #pragma unroll
                for (int fi = 0; fi < 2; fi++) {
                    float r = sigmoidf_(arz[fi][q]);
                    float z = sigmoidf_(arz[2+fi][q]);
                    float n = tanhf_(fmaf(r, hn[fi][q], xn[fi][q]));
                    float ho = hD[2*q + fi];
                    float hv = fmaf(z, ho - n, n);
                    hD[2*q + fi] = hv;
                    hl[4*kg + q][c + 16*fi] = (__bf16)hv;
                }
        }

        #pragma unroll
        for (int q = 0; q < 4; q++)
            #pragma unroll
            for (int fi = 0; fi < 2; fi++)
                h_p[(size_t)(rbase + q) * FD + c + 16*fi] = hD[2*q + fi];

        {
            int r  = lane >> 2;
            int c0 = (lane & 3) * 8;
            bf16x8 o = *(const bf16x8*)&hl[r][c0];
            *(bf16x8*)(hpb + ((size_t)(blk0 + r)) * FD + c0) = o;
        }

        if (!hasN) break;
        #pragma unroll
        for (int j = 0; j < 8; j++) ch_[j] = nh[j];
        cia = nia; cib = nib;
        tile = nt;
    }
}

// ---------------- fused gather + channel GRU2 (MFMA, preconv weights) -------
// 2-wave blocks (32 channels) -> 1563 blocks; 4-deep dual-bank gather.
__global__ __launch_bounds__(128) void gchannel_kernel(
    const __bf16* __restrict__ hpb, const int* __restrict__ offsets,
    const int* __restrict__ elist, float* __restrict__ h_c,
    const __bf16* __restrict__ w2xH, const __bf16* __restrict__ w2xL,
    const __bf16* __restrict__ w2hH, const __bf16* __restrict__ w2hL,
    const float* __restrict__ bih, const float* __restrict__ bhh,
    __bf16* __restrict__ hcb, int C)
{
    const int tid  = threadIdx.x;
    const int wid  = tid >> 6;          // 0..1
    const int lane = tid & 63;
    const int c    = lane & 15;
    const int kg   = lane >> 4;
    const int blk0 = blockIdx.x * 32;
    const int chA  = blk0 + wid*16 + c;

    // gather: 4-deep with dual accumulator banks
    float xr[8], xs[8];
    #pragma unroll
    for (int j = 0; j < 8; j++) { xr[j] = 0.f; xs[j] = 0.f; }
    int s = 0, e = 0;
    if (chA < C) { s = offsets[chA]; e = offsets[chA + 1]; }
    int i = s;
    for (; i + 4 <= e; i += 4) {
        int e0 = elist[i], e1 = elist[i + 1], e2 = elist[i + 2], e3 = elist[i + 3];
        bf16x8 v0 = *(const bf16x8*)(hpb + (size_t)e0 * FD + 8*kg);
        bf16x8 v1 = *(const bf16x8*)(hpb + (size_t)e1 * FD + 8*kg);
        bf16x8 v2 = *(const bf16x8*)(hpb + (size_t)e2 * FD + 8*kg);
        bf16x8 v3 = *(const bf16x8*)(hpb + (size_t)e3 * FD + 8*kg);
        #pragma unroll
        for (int j = 0; j < 8; j++) {
            xr[j] += (float)v0[j] + (float)v2[j];
            xs[j] += (float)v1[j] + (float)v3[j];
        }
    }
    for (; i < e; i++) {
        bf16x8 v0 = *(const bf16x8*)(hpb + (size_t)elist[i] * FD + 8*kg);
        #pragma unroll
        for (int j = 0; j < 8; j++) xr[j] += (float)v0[j];
    }
    #pragma unroll
    for (int j = 0; j < 8; j++) xr[j] += xs[j];

    float hr[8];
    if (chA < C) {
        const float4* ha = (const float4*)(h_c + (size_t)chA * FD + 8*kg);
        float4 h0 = ha[0], h1 = ha[1];
        hr[0]=h0.x; hr[1]=h0.y; hr[2]=h0.z; hr[3]=h0.w;
        hr[4]=h1.x; hr[5]=h1.y; hr[6]=h1.z; hr[7]=h1.w;
    } else {
        #pragma unroll
        for (int j = 0; j < 8; j++) hr[j] = 0.f;
    }
    bf16x8 AxH, AxL, AhH, AhL;
    #pragma unroll
    for (int j = 0; j < 8; j++) {
        __bf16 xh = (__bf16)xr[j]; AxH[j] = xh; AxL[j] = (__bf16)(xr[j] - (float)xh);
        __bf16 hh = (__bf16)hr[j]; AhH[j] = hh; AhL[j] = (__bf16)(hr[j] - (float)hh);
    }

    f32x4 cin_rz[4], cin_xn[2], cin_hn[2];
    #pragma unroll
    for (int t = 0; t < 4; t++) {
        float b = bih[16*t + c] + bhh[16*t + c];
        cin_rz[t] = (f32x4){b, b, b, b};
    }
    #pragma unroll
    for (int fi = 0; fi < 2; fi++) {
        float bi = bih[64 + 16*fi + c];
        float bh = bhh[64 + 16*fi + c];
        cin_xn[fi] = (f32x4){bi, bi, bi, bi};
        cin_hn[fi] = (f32x4){bh, bh, bh, bh};
    }

    f32x4 arz[4], xn[2], hn[2];
    #pragma unroll
    for (int t = 0; t < 4; t++) {
        size_t wo = (size_t)(16*t + c) * FD + 8*kg;
        bf16x8 BxH_ = *(const bf16x8*)(w2xH + wo);
        bf16x8 BxL_ = *(const bf16x8*)(w2xL + wo);
        bf16x8 BhH_ = *(const bf16x8*)(w2hH + wo);
        bf16x8 BhL_ = *(const bf16x8*)(w2hL + wo);
        f32x4 a = cin_rz[t];
        a = __builtin_amdgcn_mfma_f32_16x16x32_bf16(AxH, BxH_, a, 0, 0, 0);
        a = __builtin_amdgcn_mfma_f32_16x16x32_bf16(AxH, BxL_, a, 0, 0, 0);
        a = __builtin_amdgcn_mfma_f32_16x16x32_bf16(AxL, BxH_, a, 0, 0, 0);
        a = __builtin_amdgcn_mfma_f32_16x16x32_bf16(AhH, BhH_, a, 0, 0, 0);
        a = __builtin_amdgcn_mfma_f32_16x16x32_bf16(AhH, BhL_, a, 0, 0, 0);
        a = __builtin_amdgcn_mfma_f32_16x16x32_bf16(AhL, BhH_, a, 0, 0, 0);
        arz[t] = a;
    }
    #pragma unroll
    for (int fi = 0; fi < 2; fi++) {
        size_t wo = (size_t)(16*(4+fi) + c) * FD + 8*kg;
        bf16x8 BxH_ = *(const bf16x8*)(w2xH + wo);
        bf16x8 BxL_ = *(const bf16x8*)(w2xL + wo);
        bf16x8 BhH_ = *(const bf16x8*)(w2hH + wo);
        bf16x8 BhL_ = *(const bf16x8*)(w2hL + wo);
        f32x4 a = cin_xn[fi];
        a = __builtin_amdgcn_mfma_f32_16x16x32_bf16(AxH, BxH_, a, 0, 0, 0);
        a = __builtin_amdgcn_mfma_f32_16x16x32_bf16(AxH, BxL_, a, 0, 0, 0);
        a = __builtin_amdgcn_mfma_f32_16x16x32_bf16(AxL, BxH_, a, 0, 0, 0);
        xn[fi] = a;
        f32x4 b = cin_hn[fi];
        b = __builtin_amdgcn_mfma_f32_16x16x32_bf16(AhH, BhH_, b, 0, 0, 0);
        b = __builtin_amdgcn_mfma_f32_16x16x32_bf16(AhH, BhL_, b, 0, 0, 0);
        b = __builtin_amdgcn_mfma_f32_16x16x32_bf16(AhL, BhH_, b, 0, 0, 0);
        hn[fi] = b;
    }

    #pragma unroll
    for (int q = 0; q < 4; q++) {
        int row = blk0 + wid*16 + 4*kg + q;
        if (row < C) {
            #pragma unroll
            for (int fi = 0; fi < 2; fi++) {
                float r = sigmoidf_(arz[fi][q]);
                float z = sigmoidf_(arz[2+fi][q]);
                float n = tanhf_(fmaf(r, hn[fi][q], xn[fi][q]));
                float ho = h_c[(size_t)row * FD + c + 16*fi];
                float hv = fmaf(z, ho - n, n);
                h_c[(size_t)row * FD + c + 16*fi] = hv;
                hcb[(size_t)row * FD + c + 16*fi] = (__bf16)hv;
            }
        }
    }
}

// ---------------- fallback kernels (atomic path, raw weights) ---------------

__global__ __launch_bounds__(256) void path_update_kernel(
    const float* __restrict__ h_c, float* __restrict__ h_p,
    const int* __restrict__ p2c,
    const float* __restrict__ Wih, const float* __restrict__ Whh,
    const float* __restrict__ bih, const float* __restrict__ bhh, int P)
{
    int p = blockIdx.x * blockDim.x + threadIdx.x;
    if (p >= P) return;

    float h[FD];
    const float4* hp4 = (const float4*)(h_p + (size_t)p * FD);
    #pragma unroll
    for (int i = 0; i < FD / 4; i++) {
        float4 v = hp4[i];
        h[4*i] = v.x; h[4*i+1] = v.y; h[4*i+2] = v.z; h[4*i+3] = v.w;
    }

    int idx[KNB];
    const int4* pi = (const int4*)(p2c + (size_t)p * KNB);
    int4 i0 = pi[0], i1 = pi[1];
    idx[0]=i0.x; idx[1]=i0.y; idx[2]=i0.z; idx[3]=i0.w;
    idx[4]=i1.x; idx[5]=i1.y; idx[6]=i1.z; idx[7]=i1.w;

    for (int k = 0; k < KNB; k++) {
        float x[FD];
        const float4* xr = (const float4*)(h_c + (size_t)idx[k] * FD);
        #pragma unroll
        for (int i = 0; i < FD / 4; i++) {
            float4 v = xr[i];
            x[4*i] = v.x; x[4*i+1] = v.y; x[4*i+2] = v.z; x[4*i+3] = v.w;
        }

        float hn[FD];
        #pragma unroll 4
        for (int j = 0; j < FD; j++) {
            float air = bih[j],        ahr = bhh[j];
            float aiz = bih[FD + j],   ahz = bhh[FD + j];
            float ain = bih[2*FD + j], ahn = bhh[2*FD + j];
            #pragma unroll
            for (int i = 0; i < FD; i++) {
                air = fmaf(Wih[j*FD + i],          x[i], air);
                ahr = fmaf(Whh[j*FD + i],          h[i], ahr);
                aiz = fmaf(Wih[(FD + j)*FD + i],   x[i], aiz);
                ahz = fmaf(Whh[(FD + j)*FD + i],   h[i], ahz);
                ain = fmaf(Wih[(2*FD + j)*FD + i], x[i], ain);
                ahn = fmaf(Whh[(2*FD + j)*FD + i], h[i], ahn);
            }
            float r = sigmoidf_(air + ahr);
            float z = sigmoidf_(aiz + ahz);
            float n = tanhf_(ain + r * ahn);
            hn[j] = (1.0f - z) * n + z * h[j];
        }
        #pragma unroll
        for (int j = 0; j < FD; j++) h[j] = hn[j];
    }

    float4* hpw = (float4*)(h_p + (size_t)p * FD);
    #pragma unroll
    for (int i = 0; i < FD / 4; i++) {
        float4 v;
        v.x = h[4*i]; v.y = h[4*i+1]; v.z = h[4*i+2]; v.w = h[4*i+3];
        hpw[i] = v;
    }
}

__global__ __launch_bounds__(256) void scatter_agg_atomic_kernel(
    const float* __restrict__ h_p, const int* __restrict__ p2c,
    float* __restrict__ agg, int P)
{
    int p = blockIdx.x * blockDim.x + threadIdx.x;
    if (p >= P) return;
    const float* hr = h_p + (size_t)p * FD;
    #pragma unroll
    for (int k = 0; k < KNB; k++) {
        int c = p2c[(size_t)p * KNB + k];
        float* ar = agg + (size_t)c * FD;
        #pragma unroll
        for (int i = 0; i < FD; i++) atomicAdd(ar + i, hr[i]);
    }
}

__global__ __launch_bounds__(256) void channel_update_kernel(
    const float* __restrict__ agg, float* __restrict__ h_c,
    const float* __restrict__ Wih, const float* __restrict__ Whh,
    const float* __restrict__ bih, const float* __restrict__ bhh, int C)
{
    int c = blockIdx.x * blockDim.x + threadIdx.x;
    if (c >= C) return;

    float h[FD], x[FD];
    const float4* hr = (const float4*)(h_c + (size_t)c * FD);
    const float4* xr = (const float4*)(agg + (size_t)c * FD);
    #pragma unroll
    for (int i = 0; i < FD / 4; i++) {
        float4 v = hr[i];
        h[4*i] = v.x; h[4*i+1] = v.y; h[4*i+2] = v.z; h[4*i+3] = v.w;
        float4 w = xr[i];
        x[4*i] = w.x; x[4*i+1] = w.y; x[4*i+2] = w.z; x[4*i+3] = w.w;
    }

    float hn[FD];
    #pragma unroll 4
    for (int j = 0; j < FD; j++) {
        float air = bih[j],        ahr = bhh[j];
        float aiz = bih[FD + j],   ahz = bhh[FD + j];
        float ain = bih[2*FD + j], ahn = bhh[2*FD + j];
        #pragma unroll
        for (int i = 0; i < FD; i++) {
            air = fmaf(Wih[j*FD + i],          x[i], air);
            ahr = fmaf(Whh[j*FD + i],          h[i], ahr);
            aiz = fmaf(Wih[(FD + j)*FD + i],   x[i], aiz);
            ahz = fmaf(Whh[(FD + j)*FD + i],   h[i], ahz);
            ain = fmaf(Wih[(2*FD + j)*FD + i], x[i], ain);
            ahn = fmaf(Whh[(2*FD + j)*FD + i], h[i], ahn);
        }
        float r = sigmoidf_(air + ahr);
        float z = sigmoidf_(aiz + ahz);
        float n = tanhf_(ain + r * ahn);
        hn[j] = (1.0f - z) * n + z * h[j];
    }

    float4* hw = (float4*)(h_c + (size_t)c * FD);
    #pragma unroll
    for (int i = 0; i < FD / 4; i++) {
        float4 v;
        v.x = hn[4*i]; v.y = hn[4*i+1]; v.z = hn[4*i+2]; v.w = hn[4*i+3];
        hw[i] = v;
    }
}

extern "C" void kernel_launch(void* const* d_in, const int* in_sizes, int n_in,
                              void* d_out, int out_size, void* d_ws, size_t ws_size,
                              hipStream_t stream) {
    const float* paths    = (const float*)d_in[0];
    const float* channels = (const float*)d_in[1];
    const int*   p2c      = (const int*)d_in[2];
    const float* Wih1 = (const float*)d_in[3];
    const float* Whh1 = (const float*)d_in[4];
    const float* bih1 = (const float*)d_in[5];
    const float* bhh1 = (const float*)d_in[6];
    const float* Wih2 = (const float*)d_in[7];
    const float* Whh2 = (const float*)d_in[8];
    const float* bih2 = (const float*)d_in[9];
    const float* bhh2 = (const float*)d_in[10];

    const int P = in_sizes[0] / FD;     // 200000
    const int C = in_sizes[1] / FD;     // 50000
    const int E = P * KNB;              // 1.6M edges
    const int NR = (C + 255) >> 8;      // 196 buckets

    float* h_p = (float*)d_out;                  // [P*FD]
    float* h_c = h_p + (size_t)P * FD;           // [C*FD]

    // ws: bsum[NR] bbase[NR] | offsets[C+1] | bstart[NR+1] | elist[E] | hcb |
    //     wbufs(6) | UNION{ build: ebuf[E](int2)+cnt1[NCH*NR] | iter: hpb }
    char* ws = (char*)d_ws;
    size_t bs_off  = 0;
    size_t ofs_off = (bs_off + (size_t)(2 * NR) * 4 + 255) & ~(size_t)255;
    size_t bst_off = (ofs_off + (size_t)(C + 1) * 4 + 255) & ~(size_t)255;
    size_t el_off  = (bst_off + (size_t)(NR + 1) * 4 + 255) & ~(size_t)255;
    size_t hcb_off = (el_off + (size_t)E * 4 + 255) & ~(size_t)255;
    size_t wb_off  = (hcb_off + (size_t)C * FD * 2 + 255) & ~(size_t)255;
    size_t wmat_b  = (size_t)96 * FD * 2;                 // 6 KB per matrix
    size_t uni_off = (wb_off + 6 * wmat_b + 255) & ~(size_t)255;
    size_t ebuf_b  = (size_t)E * 8;
    size_t cnt1_b  = (size_t)NCH * NR * 4;
    size_t hpb_b   = (size_t)P * FD * 2;
    size_t bld_b   = ebuf_b + cnt1_b;
    size_t uni_b   = (hpb_b > bld_b) ? hpb_b : bld_b;

    int*    bsum    = (int*)(ws + bs_off);
    int*    bbase   = bsum + NR;
    int*    offsets = (int*)(ws + ofs_off);
    int*    bstart  = (int*)(ws + bst_off);
    int*    elist   = (int*)(ws + el_off);
    __bf16* hcb     = (__bf16*)(ws + hcb_off);
    __bf16* w1x     = (__bf16*)(ws + wb_off);
    __bf16* w1h     = (__bf16*)(ws + wb_off + 1 * wmat_b);
    __bf16* w2xH    = (__bf16*)(ws + wb_off + 2 * wmat_b);
    __bf16* w2xL    = (__bf16*)(ws + wb_off + 3 * wmat_b);
    __bf16* w2hH    = (__bf16*)(ws + wb_off + 4 * wmat_b);
    __bf16* w2hL    = (__bf16*)(ws + wb_off + 5 * wmat_b);
    int2*   ebuf    = (int2*)(ws + uni_off);
    int*    cnt1    = (int*)(ws + uni_off + ebuf_b);
    __bf16* hpb     = (__bf16*)(ws + uni_off);   // time-disjoint w/ ebuf/cnt1

    const bool mfma_ok = (P % 64 == 0) && (C <= 65536);
    const bool tier1 = mfma_ok && (ws_size >= uni_off + uni_b);

    dim3 pb(256), pg((P + 255) / 256);
    dim3 cb(256), cg((C + 255) / 256);

    if (tier1) {
        hipMemcpyAsync(h_p, paths, (size_t)P * FD * sizeof(float),
                       hipMemcpyDeviceToDevice, stream);
        int n8 = C * FD / 8;
        hc_init_kernel<<<(n8 + 255) / 256, 256, 0, stream>>>(channels, h_c, hcb, n8);
        wconv_kernel<<<(96 * FD + 255) / 256, 256, 0, stream>>>(
            Wih1, Whh1, Wih2, Whh2, w1x, w1h, w2xH, w2xL, w2hH, w2hL);

        bincount_kernel<<<NCH, 256, 0, stream>>>(p2c, cnt1, E, NR);
        scan_chunks_kernel<<<1, 256, 0, stream>>>(cnt1, bstart, NR, E);
        binfill_kernel<<<NCH, 256, 0, stream>>>(p2c, cnt1, ebuf, E, NR);
        buckscan_kernel<<<NR, 256, 0, stream>>>(ebuf, bstart, offsets, bsum, C);
        scan_bsums_kernel<<<1, 256, 0, stream>>>(bsum, bbase, offsets, NR, C, E);
        addback_kernel<<<cg, cb, 0, stream>>>(offsets, bbase, C);
        buckfill_kernel<<<NR, 256, 0, stream>>>(ebuf, bstart, offsets, elist, C);

        const int ntiles16 = P / 16;                    // 12500 wave-tiles
        int pgrid = ntiles16 < 4096 ? ntiles16 : 4096;  // residency fill
        dim3 xg((C + 31) / 32), xb(128);
        for (int it = 0; it < NITER; it++) {
            path_fused_kernel<<<pgrid, 64, 0, stream>>>(h_p, p2c, hcb,
                                                        w1x, w1h, bih1, bhh1,
                                                        hpb, ntiles16);
            gchannel_kernel<<<xg, xb, 0, stream>>>(hpb, offsets, elist, h_c,
                                                   w2xH, w2xL, w2hH, w2hL,
                                                   bih2, bhh2, hcb, C);
        }
    } else {
        float* agg0 = (float*)d_ws;
        size_t aggf_b = (size_t)C * FD * sizeof(float);
        hipMemcpyAsync(h_p, paths, (size_t)P * FD * sizeof(float),
                       hipMemcpyDeviceToDevice, stream);
        hipMemcpyAsync(h_c, channels, (size_t)C * FD * sizeof(float),
                       hipMemcpyDeviceToDevice, stream);
        for (int it = 0; it < NITER; it++) {
            path_update_kernel<<<pg, pb, 0, stream>>>(h_c, h_p, p2c,
                                                      Wih1, Whh1, bih1, bhh1, P);
            hipMemsetAsync(agg0, 0, aggf_b, stream);
            scatter_agg_atomic_kernel<<<pg, pb, 0, stream>>>(h_p, p2c, agg0, P);
            channel_update_kernel<<<cg, cb, 0, stream>>>(agg0, h_c,
                                                         Wih2, Whh2, bih2, bhh2, C);
        }
    }
}